// Round 12
// baseline (168.527 us; speedup 1.0000x reference)
//
#include <hip/hip_runtime.h>
#include <math.h>

#define B_TOT   1024
#define S_DIM   64
#define N_DIM   256
#define UNFOLDS 12
#define EPSF    1e-8f
#define L2E     1.4426950408889634f
#define KMAX    256
#define ECLAMP  1073741824.0f   // 2^30: clamp err <= 2^-30; quad product <= 2^121 (finite)

// Guaranteed-native transcendentals.
#if defined(__has_builtin)
#  if __has_builtin(__builtin_amdgcn_exp2f)
#    define FEXP2(x) __builtin_amdgcn_exp2f(x)
#  endif
#  if __has_builtin(__builtin_amdgcn_rcpf)
#    define FRCP(x) __builtin_amdgcn_rcpf(x)
#  endif
#endif
#ifndef FEXP2
__device__ __forceinline__ float __fexp2_asm(float x){ float r; asm("v_exp_f32 %0, %1" : "=v"(r) : "v"(x)); return r; }
#  define FEXP2(x) __fexp2_asm(x)
#endif
#ifndef FRCP
__device__ __forceinline__ float __frcp_asm(float x){ float r; asm("v_rcp_f32 %0, %1" : "=v"(r) : "v"(x)); return r; }
#  define FRCP(x) __frcp_asm(x)
#endif

__device__ __forceinline__ float softplus_f(float x) {
    return log1pf(expf(x));
}

// Montgomery batch-inversion quad: 4 sigmoids r_i = 1/(1+e_i) share ONE v_rcp.
// One param float4 p (same synapse), 4 v values (4 batches). ~1ulp exact.
// All macro locals underscore-prefixed (R9 lesson: caller-name collision).
#define MQUAD(p, v0, v1, v2, v3, m0, d0, m1, d1, m2, d2, m3, d3)            \
    {                                                                       \
        float _t0 = fmaf(p.x, v0, p.y);                                     \
        float _t1 = fmaf(p.x, v1, p.y);                                     \
        float _t2 = fmaf(p.x, v2, p.y);                                     \
        float _t3 = fmaf(p.x, v3, p.y);                                     \
        float _e0 = fminf(FEXP2(_t0), ECLAMP);                              \
        float _e1 = fminf(FEXP2(_t1), ECLAMP);                              \
        float _e2 = fminf(FEXP2(_t2), ECLAMP);                              \
        float _e3 = fminf(FEXP2(_t3), ECLAMP);                              \
        float _a0 = 1.0f + _e0, _a1 = 1.0f + _e1;                           \
        float _a2 = 1.0f + _e2, _a3 = 1.0f + _e3;                           \
        float _b01 = _a0 * _a1, _b23 = _a2 * _a3;                           \
        float _ip   = FRCP(_b01 * _b23);                                    \
        float _ip01 = _b23 * _ip, _ip23 = _b01 * _ip;                       \
        float _r0 = _a1 * _ip01, _r1 = _a0 * _ip01;                         \
        float _r2 = _a3 * _ip23, _r3 = _a2 * _ip23;                         \
        m0 = fmaf(p.w, _r0, m0); d0 = fmaf(p.z, _r0, d0);                   \
        m1 = fmaf(p.w, _r1, m1); d1 = fmaf(p.z, _r1, d1);                   \
        m2 = fmaf(p.w, _r2, m2); d2 = fmaf(p.z, _r2, d2);                   \
        m3 = fmaf(p.w, _r3, m3); d3 = fmaf(p.z, _r3, d3);                   \
    }

// ---- Stage 1: per-column live counts (static sparsity census) ----
__global__ __launch_bounds__(256)
void ltc_count(const float* __restrict__ mask, int* __restrict__ cnt)
{
    const int col = blockIdx.x, i = threadIdx.x;
    const bool live = mask[i * N_DIM + col] > 0.0f;
    const int lane = i & 63, wv = i >> 6;
    const unsigned long long ball = __ballot(live);
    __shared__ int wcnt[4];
    if (lane == 0) wcnt[wv] = __popcll(ball);
    __syncthreads();
    if (i == 0) cnt[col] = wcnt[0] + wcnt[1] + wcnt[2] + wcnt[3];
}

// ---- Stage 2: bitonic sort columns by live count (ascending) ----
// perm[slot]=col, slotof[col]=slot, qm[slot]=ceil(cnt/4). Waves of 64
// consecutive slots then have near-equal per-lane loop bounds.
__global__ __launch_bounds__(256)
void ltc_sort(const int* __restrict__ cnt, int* __restrict__ perm,
              int* __restrict__ slotof, int* __restrict__ qm)
{
    __shared__ int key[N_DIM];
    const int t = threadIdx.x;
    key[t] = (cnt[t] << 8) | t;
    __syncthreads();
    for (int k = 2; k <= N_DIM; k <<= 1) {
        for (int jj = k >> 1; jj > 0; jj >>= 1) {
            const int ixj = t ^ jj;
            if (ixj > t) {
                const int a = key[t], b = key[ixj];
                const bool asc = (t & k) == 0;
                if (asc ? (a > b) : (a < b)) { key[t] = b; key[ixj] = a; }
            }
            __syncthreads();
        }
    }
    const int kk = key[t];
    const int col = kk & 255;
    perm[t] = col;
    slotof[col] = t;
    qm[t] = ((kk >> 8) + 3) >> 2;
}

// ---- Stage 3a: sensory params {A,B,WE,WEr} written SLOT-major, and per-slot
// combine constants. sigmoid(sigma*(v-mu)) = 1/(1+exp2(A*v+B)).
__global__ void ltc_precompute_s(const float* __restrict__ gleak, const float* __restrict__ vleak,
                                 const float* __restrict__ cm,
                                 const float* __restrict__ sw,    const float* __restrict__ ssig,
                                 const float* __restrict__ smu,   const float* __restrict__ serev,
                                 const float* __restrict__ smask, const int* __restrict__ slotof,
                                 float4* __restrict__ s4, float4* __restrict__ pj)
{
    const int idx = blockIdx.x * blockDim.x + threadIdx.x;
    if (idx < S_DIM * N_DIM) {
        const int col = idx & (N_DIM - 1), s = idx >> 8;
        const int slot = slotof[col];
        float we = softplus_f(sw[idx]) * smask[idx];
        float sg = ssig[idx];
        float4 o;
        o.x = -L2E * sg;
        o.y =  L2E * sg * smu[idx];
        o.z =  we;
        o.w =  we * serev[idx];
        s4[s * N_DIM + slot] = o;
    }
    if (idx < N_DIM) {
        const int slot = slotof[idx];
        float g = softplus_f(gleak[idx]);
        float4 o;
        o.x = softplus_f(cm[idx]) * (float)UNFOLDS;  // cm_t
        o.y = g;
        o.z = g * vleak[idx];
        o.w = 0.0f;
        pj[slot] = o;
    }
}

// ---- Stage 3b: fused precompute + compaction into SLOT-major arrays.
// One block per column; ballot prefix-scan packs live rows. pc is k-major
// [k][slot] float4 (coalesced over lanes = consecutive slots); pofs same
// shape, u16 PRE-SHIFTED byte offsets (real i<<4). Pad to multiple of 4.
__global__ __launch_bounds__(256)
void ltc_compact(const float* __restrict__ w,    const float* __restrict__ sigma,
                 const float* __restrict__ mu,   const float* __restrict__ erev,
                 const float* __restrict__ mask, const int* __restrict__ slotof,
                 float4* __restrict__ pc, unsigned short* __restrict__ pofs)
{
    const int col = blockIdx.x;
    const int i   = threadIdx.x;
    const int idx = i * N_DIM + col;
    const int slot = slotof[col];

    const float mk = mask[idx];
    const bool live = mk > 0.0f;
    float we = softplus_f(w[idx]) * mk;
    float sg = sigma[idx];
    float4 o;
    o.x = -L2E * sg;
    o.y =  L2E * sg * mu[idx];
    o.z =  we;
    o.w =  we * erev[idx];

    const int lane = i & 63, wv = i >> 6;
    const unsigned long long ball = __ballot(live);
    const int lpre = __popcll(ball & ((1ull << lane) - 1ull));
    __shared__ int wcnt[4];
    if (lane == 0) wcnt[wv] = __popcll(ball);
    __syncthreads();
    int base = 0;
    #pragma unroll
    for (int ww = 0; ww < 4; ++ww) base += (ww < wv) ? wcnt[ww] : 0;
    const int total = wcnt[0] + wcnt[1] + wcnt[2] + wcnt[3];

    if (live) {
        const int pos = base + lpre;
        pc[pos * N_DIM + slot] = o;
        pofs[pos * N_DIM + slot] = (unsigned short)(i << 4);
    }
    const int K4 = (total + 3) & ~3;
    for (int k = total + i; k < K4; k += 256) {   // zero-pad (exact zeros)
        pc[k * N_DIM + slot] = make_float4(0.f, 0.f, 0.f, 0.f);
        pofs[k * N_DIM + slot] = 0;
    }
}

// ---- Stage 4: main. 1024 threads/block, 256 blocks, 4 batches each.
// slot = tid&255 (sorted column), q = tid>>8; lane loops EXACTLY qm[slot]
// quads (wave max ~ wave mean after sort). Per quad: 1 coalesced float4
// param + 1 coalesced u16 offset + 1 b128 LDS gather + Montgomery quad.
__global__ __launch_bounds__(1024, 2)
void ltc_main(const float* __restrict__ inputs, const float* __restrict__ state,
              const float4* __restrict__ pc, const unsigned short* __restrict__ pofs,
              const int* __restrict__ perm, const int* __restrict__ qm,
              const float4* __restrict__ s4, const float4* __restrict__ pj,
              float* __restrict__ out)
{
    __shared__ float4 v4[N_DIM];        // v[real i], component = batch
    __shared__ float4 pnum[4][N_DIM];   // partials [q][slot]
    __shared__ float4 pden[4][N_DIM];
    __shared__ float  in_lds[4][S_DIM];

    const int tid  = threadIdx.x;
    const int slot = tid & (N_DIM - 1);
    const int q    = tid >> 8;
    const int b0   = blockIdx.x << 2;

    // init v by REAL neuron id (coalesced)
    ((float*)v4)[(slot << 2) + q] = state[(b0 + q) * N_DIM + slot];
    if (tid < 4 * S_DIM) in_lds[tid >> 6][tid & 63] = inputs[b0 * S_DIM + tid];

    const int   col = perm[slot];       // real column this lane owns
    const int   myq = qm[slot];         // per-lane exact quad count
    const float4 c  = pj[slot];
    const float cmt = c.x, gl = c.y, glv = c.z;
    const float cg  = cmt + gl + EPSF;
    __syncthreads();

    // ---- sensory pass: q covers s in [16q, 16q+16), Montgomery quads ----
    float n0 = 0.f, n1 = 0.f, n2 = 0.f, n3 = 0.f;
    float d0 = 0.f, d1 = 0.f, d2 = 0.f, d3 = 0.f;
    {
        const float4* __restrict__ sr = s4 + (q << 4) * N_DIM + slot;
        const int sb = q << 4;
        #pragma unroll 4
        for (int s = 0; s < 16; ++s) {
            const float4 p = sr[s * N_DIM];
            const float i0 = in_lds[0][sb + s];
            const float i1 = in_lds[1][sb + s];
            const float i2 = in_lds[2][sb + s];
            const float i3 = in_lds[3][sb + s];
            MQUAD(p, i0, i1, i2, i3, n0, d0, n1, d1, n2, d2, n3, d3)
        }
    }
    pnum[q][slot] = make_float4(n0, n1, n2, n3);
    pden[q][slot] = make_float4(d0, d1, d2, d3);
    __syncthreads();

    // redundant sensory reduce into registers (all q identical)
    float4 sn = make_float4(0.f, 0.f, 0.f, 0.f);
    float4 sd = make_float4(0.f, 0.f, 0.f, 0.f);
    #pragma unroll
    for (int qq = 0; qq < 4; ++qq) {
        const float4 a = pnum[qq][slot], b = pden[qq][slot];
        sn.x += a.x; sn.y += a.y; sn.z += a.z; sn.w += a.w;
        sd.x += b.x; sd.y += b.y; sd.z += b.z; sd.w += b.w;
    }
    __syncthreads();   // pnum/pden reused below

    // ---- 12 ODE unfolds: lane's k-range = [q*myq, (q+1)*myq) ----
    const float4*         __restrict__ pr = pc   + (q * myq) * N_DIM + slot;
    const unsigned short* __restrict__ po = pofs + (q * myq) * N_DIM + slot;

    #pragma unroll 1
    for (int step = 0; step < UNFOLDS; ++step) {
        float m0 = 0.f, m1 = 0.f, m2 = 0.f, m3 = 0.f;
        float h0 = 0.f, h1 = 0.f, h2 = 0.f, h3 = 0.f;

        #pragma unroll 4
        for (int t = 0; t < myq; ++t) {
            const float4 p   = pr[t * N_DIM];          // coalesced dwordx4
            const int    off = (int)po[t * N_DIM];     // coalesced u16 (real i<<4)
            const float4 vv  = *(const float4*)((const char*)v4 + off);  // b128 gather
            MQUAD(p, vv.x, vv.y, vv.z, vv.w, m0, h0, m1, h1, m2, h2, m3, h3)
        }

        const float4 vo = v4[col];   // read old v (real col) BEFORE the barrier
        pnum[q][slot] = make_float4(m0, m1, m2, m3);
        pden[q][slot] = make_float4(h0, h1, h2, h3);
        __syncthreads();

        // redundant combine in all q-groups (bitwise-identical results);
        // Montgomery for the 4 division denominators (all > cg > 0).
        float4 tn = sn, td = sd;
        #pragma unroll
        for (int qq = 0; qq < 4; ++qq) {
            const float4 a = pnum[qq][slot], b = pden[qq][slot];
            tn.x += a.x; tn.y += a.y; tn.z += a.z; tn.w += a.w;
            td.x += b.x; td.y += b.y; td.z += b.z; td.w += b.w;
        }
        const float g0 = cg + td.x, g1 = cg + td.y;
        const float g2 = cg + td.z, g3 = cg + td.w;
        const float b01 = g0 * g1, b23 = g2 * g3;
        const float ip   = FRCP(b01 * b23);
        const float ip01 = b23 * ip, ip23 = b01 * ip;
        float4 vn;
        vn.x = (fmaf(cmt, vo.x, glv) + tn.x) * (g1 * ip01);
        vn.y = (fmaf(cmt, vo.y, glv) + tn.y) * (g0 * ip01);
        vn.z = (fmaf(cmt, vo.z, glv) + tn.z) * (g3 * ip23);
        vn.w = (fmaf(cmt, vo.w, glv) + tn.w) * (g2 * ip23);
        v4[col] = vn;              // scatter by perm; 4 writers, identical bits
        __syncthreads();
    }

    // writeback: scatter to real column (once per kernel)
    out[(b0 + q) * N_DIM + col] = ((const float*)v4)[(col << 2) + q];
}

extern "C" void kernel_launch(void* const* d_in, const int* in_sizes, int n_in,
                              void* d_out, int out_size, void* d_ws, size_t ws_size,
                              hipStream_t stream)
{
    const float* inputs = (const float*)d_in[0];
    const float* state  = (const float*)d_in[1];
    const float* gleak  = (const float*)d_in[2];
    const float* vleak  = (const float*)d_in[3];
    const float* cm     = (const float*)d_in[4];
    const float* w      = (const float*)d_in[5];
    const float* sigma  = (const float*)d_in[6];
    const float* mu     = (const float*)d_in[7];
    const float* erev   = (const float*)d_in[8];
    const float* sw     = (const float*)d_in[9];
    const float* ssig   = (const float*)d_in[10];
    const float* smu    = (const float*)d_in[11];
    const float* serev  = (const float*)d_in[12];
    const float* mask   = (const float*)d_in[13];
    const float* smask  = (const float*)d_in[14];

    float4* s4 = (float4*)d_ws;                        // [S*N]    = 256 KiB
    float4* pj = s4 + S_DIM * N_DIM;                   // [N]      = 4 KiB
    float4* pc = pj + N_DIM;                           // [KMAX*N] = 1 MiB
    unsigned short* pofs = (unsigned short*)(pc + KMAX * N_DIM);  // = 128 KiB
    int* cnt    = (int*)(pofs + KMAX * N_DIM);         // [N]
    int* perm   = cnt + N_DIM;                         // [N]
    int* slotof = perm + N_DIM;                        // [N]
    int* qm     = slotof + N_DIM;                      // [N]

    ltc_count<<<N_DIM, 256, 0, stream>>>(mask, cnt);
    ltc_sort<<<1, N_DIM, 0, stream>>>(cnt, perm, slotof, qm);

    ltc_precompute_s<<<(S_DIM * N_DIM + 255) / 256, 256, 0, stream>>>(
        gleak, vleak, cm, sw, ssig, smu, serev, smask, slotof, s4, pj);

    ltc_compact<<<N_DIM, 256, 0, stream>>>(w, sigma, mu, erev, mask, slotof, pc, pofs);

    ltc_main<<<B_TOT / 4, 1024, 0, stream>>>(inputs, state, pc, pofs, perm, qm,
                                             s4, pj, (float*)d_out);
}

// Round 13
// 168.520 us; speedup vs baseline: 1.0000x; 1.0000x over previous
//
#include <hip/hip_runtime.h>
#include <math.h>

#define B_TOT   1024
#define S_DIM   64
#define N_DIM   256
#define UNFOLDS 12
#define EPSF    1e-8f
#define L2E     1.4426950408889634f
#define KMAX    256
#define ECLAMP  1073741824.0f   // 2^30: clamp err <= 2^-30; quad product <= 2^121 (finite)

// Guaranteed-native transcendentals.
#if defined(__has_builtin)
#  if __has_builtin(__builtin_amdgcn_exp2f)
#    define FEXP2(x) __builtin_amdgcn_exp2f(x)
#  endif
#  if __has_builtin(__builtin_amdgcn_rcpf)
#    define FRCP(x) __builtin_amdgcn_rcpf(x)
#  endif
#endif
#ifndef FEXP2
__device__ __forceinline__ float __fexp2_asm(float x){ float r; asm("v_exp_f32 %0, %1" : "=v"(r) : "v"(x)); return r; }
#  define FEXP2(x) __fexp2_asm(x)
#endif
#ifndef FRCP
__device__ __forceinline__ float __frcp_asm(float x){ float r; asm("v_rcp_f32 %0, %1" : "=v"(r) : "v"(x)); return r; }
#  define FRCP(x) __frcp_asm(x)
#endif

__device__ __forceinline__ float softplus_f(float x) {
    return log1pf(expf(x));
}

// Montgomery batch-inversion quad: 4 sigmoids r_i = 1/(1+e_i) share ONE v_rcp.
// One param float4 p (same synapse), 4 v values (4 batches). ~1ulp exact.
// All macro locals underscore-prefixed (R9 lesson: caller-name collision).
#define MQUAD(p, v0, v1, v2, v3, m0, d0, m1, d1, m2, d2, m3, d3)            \
    {                                                                       \
        float _t0 = fmaf(p.x, v0, p.y);                                     \
        float _t1 = fmaf(p.x, v1, p.y);                                     \
        float _t2 = fmaf(p.x, v2, p.y);                                     \
        float _t3 = fmaf(p.x, v3, p.y);                                     \
        float _e0 = fminf(FEXP2(_t0), ECLAMP);                              \
        float _e1 = fminf(FEXP2(_t1), ECLAMP);                              \
        float _e2 = fminf(FEXP2(_t2), ECLAMP);                              \
        float _e3 = fminf(FEXP2(_t3), ECLAMP);                              \
        float _a0 = 1.0f + _e0, _a1 = 1.0f + _e1;                           \
        float _a2 = 1.0f + _e2, _a3 = 1.0f + _e3;                           \
        float _b01 = _a0 * _a1, _b23 = _a2 * _a3;                           \
        float _ip   = FRCP(_b01 * _b23);                                    \
        float _ip01 = _b23 * _ip, _ip23 = _b01 * _ip;                       \
        float _r0 = _a1 * _ip01, _r1 = _a0 * _ip01;                         \
        float _r2 = _a3 * _ip23, _r3 = _a2 * _ip23;                         \
        m0 = fmaf(p.w, _r0, m0); d0 = fmaf(p.z, _r0, d0);                   \
        m1 = fmaf(p.w, _r1, m1); d1 = fmaf(p.z, _r1, d1);                   \
        m2 = fmaf(p.w, _r2, m2); d2 = fmaf(p.z, _r2, d2);                   \
        m3 = fmaf(p.w, _r3, m3); d3 = fmaf(p.z, _r3, d3);                   \
    }

// ---- Stage 1: per-column live counts (static sparsity census) ----
__global__ __launch_bounds__(256)
void ltc_count(const float* __restrict__ mask, int* __restrict__ cnt)
{
    const int col = blockIdx.x, i = threadIdx.x;
    const bool live = mask[i * N_DIM + col] > 0.0f;
    const int lane = i & 63, wv = i >> 6;
    const unsigned long long ball = __ballot(live);
    __shared__ int wcnt[4];
    if (lane == 0) wcnt[wv] = __popcll(ball);
    __syncthreads();
    if (i == 0) cnt[col] = wcnt[0] + wcnt[1] + wcnt[2] + wcnt[3];
}

// ---- Stage 2: bitonic sort columns by live count (ascending) ----
// perm[slot]=col, slotof[col]=slot, qm[slot]=ceil(cnt/4). Waves of 64
// consecutive slots then have near-equal per-lane loop bounds.
__global__ __launch_bounds__(256)
void ltc_sort(const int* __restrict__ cnt, int* __restrict__ perm,
              int* __restrict__ slotof, int* __restrict__ qm)
{
    __shared__ int key[N_DIM];
    const int t = threadIdx.x;
    key[t] = (cnt[t] << 8) | t;
    __syncthreads();
    for (int k = 2; k <= N_DIM; k <<= 1) {
        for (int jj = k >> 1; jj > 0; jj >>= 1) {
            const int ixj = t ^ jj;
            if (ixj > t) {
                const int a = key[t], b = key[ixj];
                const bool asc = (t & k) == 0;
                if (asc ? (a > b) : (a < b)) { key[t] = b; key[ixj] = a; }
            }
            __syncthreads();
        }
    }
    const int kk = key[t];
    const int col = kk & 255;
    perm[t] = col;
    slotof[col] = t;
    qm[t] = ((kk >> 8) + 3) >> 2;
}

// ---- Stage 3a: sensory params {A,B,WE,WEr} written SLOT-major, and per-slot
// combine constants. sigmoid(sigma*(v-mu)) = 1/(1+exp2(A*v+B)).
__global__ void ltc_precompute_s(const float* __restrict__ gleak, const float* __restrict__ vleak,
                                 const float* __restrict__ cm,
                                 const float* __restrict__ sw,    const float* __restrict__ ssig,
                                 const float* __restrict__ smu,   const float* __restrict__ serev,
                                 const float* __restrict__ smask, const int* __restrict__ slotof,
                                 float4* __restrict__ s4, float4* __restrict__ pj)
{
    const int idx = blockIdx.x * blockDim.x + threadIdx.x;
    if (idx < S_DIM * N_DIM) {
        const int col = idx & (N_DIM - 1), s = idx >> 8;
        const int slot = slotof[col];
        float we = softplus_f(sw[idx]) * smask[idx];
        float sg = ssig[idx];
        float4 o;
        o.x = -L2E * sg;
        o.y =  L2E * sg * smu[idx];
        o.z =  we;
        o.w =  we * serev[idx];
        s4[s * N_DIM + slot] = o;
    }
    if (idx < N_DIM) {
        const int slot = slotof[idx];
        float g = softplus_f(gleak[idx]);
        float4 o;
        o.x = softplus_f(cm[idx]) * (float)UNFOLDS;  // cm_t
        o.y = g;
        o.z = g * vleak[idx];
        o.w = 0.0f;
        pj[slot] = o;
    }
}

// ---- Stage 3b: fused precompute + compaction into SLOT-major arrays.
// One block per column; ballot prefix-scan packs live rows. pc is k-major
// [k][slot] float4 (coalesced over lanes = consecutive slots); pofs same
// shape, u16 PRE-SHIFTED byte offsets (real i<<4). Pad to multiple of 4.
__global__ __launch_bounds__(256)
void ltc_compact(const float* __restrict__ w,    const float* __restrict__ sigma,
                 const float* __restrict__ mu,   const float* __restrict__ erev,
                 const float* __restrict__ mask, const int* __restrict__ slotof,
                 float4* __restrict__ pc, unsigned short* __restrict__ pofs)
{
    const int col = blockIdx.x;
    const int i   = threadIdx.x;
    const int idx = i * N_DIM + col;
    const int slot = slotof[col];

    const float mk = mask[idx];
    const bool live = mk > 0.0f;
    float we = softplus_f(w[idx]) * mk;
    float sg = sigma[idx];
    float4 o;
    o.x = -L2E * sg;
    o.y =  L2E * sg * mu[idx];
    o.z =  we;
    o.w =  we * erev[idx];

    const int lane = i & 63, wv = i >> 6;
    const unsigned long long ball = __ballot(live);
    const int lpre = __popcll(ball & ((1ull << lane) - 1ull));
    __shared__ int wcnt[4];
    if (lane == 0) wcnt[wv] = __popcll(ball);
    __syncthreads();
    int base = 0;
    #pragma unroll
    for (int ww = 0; ww < 4; ++ww) base += (ww < wv) ? wcnt[ww] : 0;
    const int total = wcnt[0] + wcnt[1] + wcnt[2] + wcnt[3];

    if (live) {
        const int pos = base + lpre;
        pc[pos * N_DIM + slot] = o;
        pofs[pos * N_DIM + slot] = (unsigned short)(i << 4);
    }
    const int K4 = (total + 3) & ~3;
    for (int k = total + i; k < K4; k += 256) {   // zero-pad (exact zeros)
        pc[k * N_DIM + slot] = make_float4(0.f, 0.f, 0.f, 0.f);
        pofs[k * N_DIM + slot] = 0;
    }
}

// ---- Stage 4: main. 1024 threads/block, 256 blocks, 4 batches each.
// slot = tid&255 (sorted column), q = tid>>8; lane loops EXACTLY qm[slot]
// quads (wave max ~ wave mean after sort). Per quad: 1 coalesced float4
// param + 1 coalesced u16 offset + 1 b128 LDS gather + Montgomery quad.
__global__ __launch_bounds__(1024, 2)
void ltc_main(const float* __restrict__ inputs, const float* __restrict__ state,
              const float4* __restrict__ pc, const unsigned short* __restrict__ pofs,
              const int* __restrict__ perm, const int* __restrict__ qm,
              const float4* __restrict__ s4, const float4* __restrict__ pj,
              float* __restrict__ out)
{
    __shared__ float4 v4[N_DIM];        // v[real i], component = batch
    __shared__ float4 pnum[4][N_DIM];   // partials [q][slot]
    __shared__ float4 pden[4][N_DIM];
    __shared__ float  in_lds[4][S_DIM];

    const int tid  = threadIdx.x;
    const int slot = tid & (N_DIM - 1);
    const int q    = tid >> 8;
    const int b0   = blockIdx.x << 2;

    // init v by REAL neuron id (coalesced)
    ((float*)v4)[(slot << 2) + q] = state[(b0 + q) * N_DIM + slot];
    if (tid < 4 * S_DIM) in_lds[tid >> 6][tid & 63] = inputs[b0 * S_DIM + tid];

    const int   col = perm[slot];       // real column this lane owns
    const int   myq = qm[slot];         // per-lane exact quad count
    const float4 c  = pj[slot];
    const float cmt = c.x, gl = c.y, glv = c.z;
    const float cg  = cmt + gl + EPSF;
    __syncthreads();

    // ---- sensory pass: q covers s in [16q, 16q+16), Montgomery quads ----
    float n0 = 0.f, n1 = 0.f, n2 = 0.f, n3 = 0.f;
    float d0 = 0.f, d1 = 0.f, d2 = 0.f, d3 = 0.f;
    {
        const float4* __restrict__ sr = s4 + (q << 4) * N_DIM + slot;
        const int sb = q << 4;
        #pragma unroll 4
        for (int s = 0; s < 16; ++s) {
            const float4 p = sr[s * N_DIM];
            const float i0 = in_lds[0][sb + s];
            const float i1 = in_lds[1][sb + s];
            const float i2 = in_lds[2][sb + s];
            const float i3 = in_lds[3][sb + s];
            MQUAD(p, i0, i1, i2, i3, n0, d0, n1, d1, n2, d2, n3, d3)
        }
    }
    pnum[q][slot] = make_float4(n0, n1, n2, n3);
    pden[q][slot] = make_float4(d0, d1, d2, d3);
    __syncthreads();

    // redundant sensory reduce into registers (all q identical)
    float4 sn = make_float4(0.f, 0.f, 0.f, 0.f);
    float4 sd = make_float4(0.f, 0.f, 0.f, 0.f);
    #pragma unroll
    for (int qq = 0; qq < 4; ++qq) {
        const float4 a = pnum[qq][slot], b = pden[qq][slot];
        sn.x += a.x; sn.y += a.y; sn.z += a.z; sn.w += a.w;
        sd.x += b.x; sd.y += b.y; sd.z += b.z; sd.w += b.w;
    }
    __syncthreads();   // pnum/pden reused below

    // ---- 12 ODE unfolds: lane's k-range = [q*myq, (q+1)*myq) ----
    const float4*         __restrict__ pr = pc   + (q * myq) * N_DIM + slot;
    const unsigned short* __restrict__ po = pofs + (q * myq) * N_DIM + slot;

    #pragma unroll 1
    for (int step = 0; step < UNFOLDS; ++step) {
        float m0 = 0.f, m1 = 0.f, m2 = 0.f, m3 = 0.f;
        float h0 = 0.f, h1 = 0.f, h2 = 0.f, h3 = 0.f;

        #pragma unroll 4
        for (int t = 0; t < myq; ++t) {
            const float4 p   = pr[t * N_DIM];          // coalesced dwordx4
            const int    off = (int)po[t * N_DIM];     // coalesced u16 (real i<<4)
            const float4 vv  = *(const float4*)((const char*)v4 + off);  // b128 gather
            MQUAD(p, vv.x, vv.y, vv.z, vv.w, m0, h0, m1, h1, m2, h2, m3, h3)
        }

        const float4 vo = v4[col];   // read old v (real col) BEFORE the barrier
        pnum[q][slot] = make_float4(m0, m1, m2, m3);
        pden[q][slot] = make_float4(h0, h1, h2, h3);
        __syncthreads();

        // redundant combine in all q-groups (bitwise-identical results);
        // Montgomery for the 4 division denominators (all > cg > 0).
        float4 tn = sn, td = sd;
        #pragma unroll
        for (int qq = 0; qq < 4; ++qq) {
            const float4 a = pnum[qq][slot], b = pden[qq][slot];
            tn.x += a.x; tn.y += a.y; tn.z += a.z; tn.w += a.w;
            td.x += b.x; td.y += b.y; td.z += b.z; td.w += b.w;
        }
        const float g0 = cg + td.x, g1 = cg + td.y;
        const float g2 = cg + td.z, g3 = cg + td.w;
        const float b01 = g0 * g1, b23 = g2 * g3;
        const float ip   = FRCP(b01 * b23);
        const float ip01 = b23 * ip, ip23 = b01 * ip;
        float4 vn;
        vn.x = (fmaf(cmt, vo.x, glv) + tn.x) * (g1 * ip01);
        vn.y = (fmaf(cmt, vo.y, glv) + tn.y) * (g0 * ip01);
        vn.z = (fmaf(cmt, vo.z, glv) + tn.z) * (g3 * ip23);
        vn.w = (fmaf(cmt, vo.w, glv) + tn.w) * (g2 * ip23);
        v4[col] = vn;              // scatter by perm; 4 writers, identical bits
        __syncthreads();
    }

    // writeback: scatter to real column (once per kernel)
    out[(b0 + q) * N_DIM + col] = ((const float*)v4)[(col << 2) + q];
}

extern "C" void kernel_launch(void* const* d_in, const int* in_sizes, int n_in,
                              void* d_out, int out_size, void* d_ws, size_t ws_size,
                              hipStream_t stream)
{
    const float* inputs = (const float*)d_in[0];
    const float* state  = (const float*)d_in[1];
    const float* gleak  = (const float*)d_in[2];
    const float* vleak  = (const float*)d_in[3];
    const float* cm     = (const float*)d_in[4];
    const float* w      = (const float*)d_in[5];
    const float* sigma  = (const float*)d_in[6];
    const float* mu     = (const float*)d_in[7];
    const float* erev   = (const float*)d_in[8];
    const float* sw     = (const float*)d_in[9];
    const float* ssig   = (const float*)d_in[10];
    const float* smu    = (const float*)d_in[11];
    const float* serev  = (const float*)d_in[12];
    const float* mask   = (const float*)d_in[13];
    const float* smask  = (const float*)d_in[14];

    float4* s4 = (float4*)d_ws;                        // [S*N]    = 256 KiB
    float4* pj = s4 + S_DIM * N_DIM;                   // [N]      = 4 KiB
    float4* pc = pj + N_DIM;                           // [KMAX*N] = 1 MiB
    unsigned short* pofs = (unsigned short*)(pc + KMAX * N_DIM);  // = 128 KiB
    int* cnt    = (int*)(pofs + KMAX * N_DIM);         // [N]
    int* perm   = cnt + N_DIM;                         // [N]
    int* slotof = perm + N_DIM;                        // [N]
    int* qm     = slotof + N_DIM;                      // [N]

    ltc_count<<<N_DIM, 256, 0, stream>>>(mask, cnt);
    ltc_sort<<<1, N_DIM, 0, stream>>>(cnt, perm, slotof, qm);

    ltc_precompute_s<<<(S_DIM * N_DIM + 255) / 256, 256, 0, stream>>>(
        gleak, vleak, cm, sw, ssig, smu, serev, smask, slotof, s4, pj);

    ltc_compact<<<N_DIM, 256, 0, stream>>>(w, sigma, mu, erev, mask, slotof, pc, pofs);

    ltc_main<<<B_TOT / 4, 1024, 0, stream>>>(inputs, state, pc, pofs, perm, qm,
                                             s4, pj, (float*)d_out);
}

// Round 14
// 168.265 us; speedup vs baseline: 1.0016x; 1.0015x over previous
//
#include <hip/hip_runtime.h>
#include <math.h>

#define B_TOT   1024
#define S_DIM   64
#define N_DIM   256
#define UNFOLDS 12
#define EPSF    1e-8f
#define L2E     1.4426950408889634f
#define KMAX    256
#define ECLAMP  1073741824.0f   // 2^30: clamp err <= 2^-30; quad product <= 2^121 (finite)

// Guaranteed-native transcendentals.
#if defined(__has_builtin)
#  if __has_builtin(__builtin_amdgcn_exp2f)
#    define FEXP2(x) __builtin_amdgcn_exp2f(x)
#  endif
#  if __has_builtin(__builtin_amdgcn_rcpf)
#    define FRCP(x) __builtin_amdgcn_rcpf(x)
#  endif
#endif
#ifndef FEXP2
__device__ __forceinline__ float __fexp2_asm(float x){ float r; asm("v_exp_f32 %0, %1" : "=v"(r) : "v"(x)); return r; }
#  define FEXP2(x) __fexp2_asm(x)
#endif
#ifndef FRCP
__device__ __forceinline__ float __frcp_asm(float x){ float r; asm("v_rcp_f32 %0, %1" : "=v"(r) : "v"(x)); return r; }
#  define FRCP(x) __frcp_asm(x)
#endif

__device__ __forceinline__ float softplus_f(float x) {
    return log1pf(expf(x));
}

// Montgomery batch-inversion quad: 4 sigmoids r_i = 1/(1+e_i) share ONE v_rcp.
// One param float4 p (same synapse), 4 v values (4 batches). ~1ulp exact.
// All macro locals underscore-prefixed (R9 lesson: caller-name collision).
#define MQUAD(p, v0, v1, v2, v3, m0, d0, m1, d1, m2, d2, m3, d3)            \
    {                                                                       \
        float _t0 = fmaf(p.x, v0, p.y);                                     \
        float _t1 = fmaf(p.x, v1, p.y);                                     \
        float _t2 = fmaf(p.x, v2, p.y);                                     \
        float _t3 = fmaf(p.x, v3, p.y);                                     \
        float _e0 = fminf(FEXP2(_t0), ECLAMP);                              \
        float _e1 = fminf(FEXP2(_t1), ECLAMP);                              \
        float _e2 = fminf(FEXP2(_t2), ECLAMP);                              \
        float _e3 = fminf(FEXP2(_t3), ECLAMP);                              \
        float _a0 = 1.0f + _e0, _a1 = 1.0f + _e1;                           \
        float _a2 = 1.0f + _e2, _a3 = 1.0f + _e3;                           \
        float _b01 = _a0 * _a1, _b23 = _a2 * _a3;                           \
        float _ip   = FRCP(_b01 * _b23);                                    \
        float _ip01 = _b23 * _ip, _ip23 = _b01 * _ip;                       \
        float _r0 = _a1 * _ip01, _r1 = _a0 * _ip01;                         \
        float _r2 = _a3 * _ip23, _r3 = _a2 * _ip23;                         \
        m0 = fmaf(p.w, _r0, m0); d0 = fmaf(p.z, _r0, d0);                   \
        m1 = fmaf(p.w, _r1, m1); d1 = fmaf(p.z, _r1, d1);                   \
        m2 = fmaf(p.w, _r2, m2); d2 = fmaf(p.z, _r2, d2);                   \
        m3 = fmaf(p.w, _r3, m3); d3 = fmaf(p.z, _r3, d3);                   \
    }

// ---- Stage 1: per-column live counts (static sparsity census) ----
__global__ __launch_bounds__(256)
void ltc_count(const float* __restrict__ mask, int* __restrict__ cnt)
{
    const int col = blockIdx.x, i = threadIdx.x;
    const bool live = mask[i * N_DIM + col] > 0.0f;
    const int lane = i & 63, wv = i >> 6;
    const unsigned long long ball = __ballot(live);
    __shared__ int wcnt[4];
    if (lane == 0) wcnt[wv] = __popcll(ball);
    __syncthreads();
    if (i == 0) cnt[col] = wcnt[0] + wcnt[1] + wcnt[2] + wcnt[3];
}

// ---- Stage 2: bitonic sort columns by live count (ascending) ----
// perm[slot]=col, slotof[col]=slot, qm[slot]=ceil(cnt/4). Waves of 64
// consecutive slots then have near-equal per-lane loop bounds.
__global__ __launch_bounds__(256)
void ltc_sort(const int* __restrict__ cnt, int* __restrict__ perm,
              int* __restrict__ slotof, int* __restrict__ qm)
{
    __shared__ int key[N_DIM];
    const int t = threadIdx.x;
    key[t] = (cnt[t] << 8) | t;
    __syncthreads();
    for (int k = 2; k <= N_DIM; k <<= 1) {
        for (int jj = k >> 1; jj > 0; jj >>= 1) {
            const int ixj = t ^ jj;
            if (ixj > t) {
                const int a = key[t], b = key[ixj];
                const bool asc = (t & k) == 0;
                if (asc ? (a > b) : (a < b)) { key[t] = b; key[ixj] = a; }
            }
            __syncthreads();
        }
    }
    const int kk = key[t];
    const int col = kk & 255;
    perm[t] = col;
    slotof[col] = t;
    qm[t] = ((kk >> 8) + 3) >> 2;
}

// ---- Stage 3a: sensory params {A,B,WE,WEr} written SLOT-major, and per-slot
// combine constants. sigmoid(sigma*(v-mu)) = 1/(1+exp2(A*v+B)).
__global__ void ltc_precompute_s(const float* __restrict__ gleak, const float* __restrict__ vleak,
                                 const float* __restrict__ cm,
                                 const float* __restrict__ sw,    const float* __restrict__ ssig,
                                 const float* __restrict__ smu,   const float* __restrict__ serev,
                                 const float* __restrict__ smask, const int* __restrict__ slotof,
                                 float4* __restrict__ s4, float4* __restrict__ pj)
{
    const int idx = blockIdx.x * blockDim.x + threadIdx.x;
    if (idx < S_DIM * N_DIM) {
        const int col = idx & (N_DIM - 1), s = idx >> 8;
        const int slot = slotof[col];
        float we = softplus_f(sw[idx]) * smask[idx];
        float sg = ssig[idx];
        float4 o;
        o.x = -L2E * sg;
        o.y =  L2E * sg * smu[idx];
        o.z =  we;
        o.w =  we * serev[idx];
        s4[s * N_DIM + slot] = o;
    }
    if (idx < N_DIM) {
        const int slot = slotof[idx];
        float g = softplus_f(gleak[idx]);
        float4 o;
        o.x = softplus_f(cm[idx]) * (float)UNFOLDS;  // cm_t
        o.y = g;
        o.z = g * vleak[idx];
        o.w = 0.0f;
        pj[slot] = o;
    }
}

// ---- Stage 3b: fused precompute + compaction into SLOT-major arrays.
// One block per column; ballot prefix-scan packs live rows. pc is k-major
// [k][slot] float4 (coalesced over lanes = consecutive slots); pofs same
// shape, u16 PRE-SHIFTED byte offsets (real i<<4). Pad to multiple of 4.
__global__ __launch_bounds__(256)
void ltc_compact(const float* __restrict__ w,    const float* __restrict__ sigma,
                 const float* __restrict__ mu,   const float* __restrict__ erev,
                 const float* __restrict__ mask, const int* __restrict__ slotof,
                 float4* __restrict__ pc, unsigned short* __restrict__ pofs)
{
    const int col = blockIdx.x;
    const int i   = threadIdx.x;
    const int idx = i * N_DIM + col;
    const int slot = slotof[col];

    const float mk = mask[idx];
    const bool live = mk > 0.0f;
    float we = softplus_f(w[idx]) * mk;
    float sg = sigma[idx];
    float4 o;
    o.x = -L2E * sg;
    o.y =  L2E * sg * mu[idx];
    o.z =  we;
    o.w =  we * erev[idx];

    const int lane = i & 63, wv = i >> 6;
    const unsigned long long ball = __ballot(live);
    const int lpre = __popcll(ball & ((1ull << lane) - 1ull));
    __shared__ int wcnt[4];
    if (lane == 0) wcnt[wv] = __popcll(ball);
    __syncthreads();
    int base = 0;
    #pragma unroll
    for (int ww = 0; ww < 4; ++ww) base += (ww < wv) ? wcnt[ww] : 0;
    const int total = wcnt[0] + wcnt[1] + wcnt[2] + wcnt[3];

    if (live) {
        const int pos = base + lpre;
        pc[pos * N_DIM + slot] = o;
        pofs[pos * N_DIM + slot] = (unsigned short)(i << 4);
    }
    const int K4 = (total + 3) & ~3;
    for (int k = total + i; k < K4; k += 256) {   // zero-pad (exact zeros)
        pc[k * N_DIM + slot] = make_float4(0.f, 0.f, 0.f, 0.f);
        pofs[k * N_DIM + slot] = 0;
    }
}

// ---- Stage 4: main. 1024 threads/block, 256 blocks, 4 batches each.
// slot = tid&255 (sorted column), q = tid>>8; lane loops EXACTLY qm[slot]
// quads (wave max ~ wave mean after sort). Per quad: 1 coalesced float4
// param + 1 coalesced u16 offset + 1 b128 LDS gather + Montgomery quad.
__global__ __launch_bounds__(1024, 2)
void ltc_main(const float* __restrict__ inputs, const float* __restrict__ state,
              const float4* __restrict__ pc, const unsigned short* __restrict__ pofs,
              const int* __restrict__ perm, const int* __restrict__ qm,
              const float4* __restrict__ s4, const float4* __restrict__ pj,
              float* __restrict__ out)
{
    __shared__ float4 v4[N_DIM];        // v[real i], component = batch
    __shared__ float4 pnum[4][N_DIM];   // partials [q][slot]
    __shared__ float4 pden[4][N_DIM];
    __shared__ float  in_lds[4][S_DIM];

    const int tid  = threadIdx.x;
    const int slot = tid & (N_DIM - 1);
    const int q    = tid >> 8;
    const int b0   = blockIdx.x << 2;

    // init v by REAL neuron id (coalesced)
    ((float*)v4)[(slot << 2) + q] = state[(b0 + q) * N_DIM + slot];
    if (tid < 4 * S_DIM) in_lds[tid >> 6][tid & 63] = inputs[b0 * S_DIM + tid];

    const int   col = perm[slot];       // real column this lane owns
    const int   myq = qm[slot];         // per-lane exact quad count
    const float4 c  = pj[slot];
    const float cmt = c.x, gl = c.y, glv = c.z;
    const float cg  = cmt + gl + EPSF;
    __syncthreads();

    // ---- sensory pass: q covers s in [16q, 16q+16), Montgomery quads ----
    float n0 = 0.f, n1 = 0.f, n2 = 0.f, n3 = 0.f;
    float d0 = 0.f, d1 = 0.f, d2 = 0.f, d3 = 0.f;
    {
        const float4* __restrict__ sr = s4 + (q << 4) * N_DIM + slot;
        const int sb = q << 4;
        #pragma unroll 4
        for (int s = 0; s < 16; ++s) {
            const float4 p = sr[s * N_DIM];
            const float i0 = in_lds[0][sb + s];
            const float i1 = in_lds[1][sb + s];
            const float i2 = in_lds[2][sb + s];
            const float i3 = in_lds[3][sb + s];
            MQUAD(p, i0, i1, i2, i3, n0, d0, n1, d1, n2, d2, n3, d3)
        }
    }
    pnum[q][slot] = make_float4(n0, n1, n2, n3);
    pden[q][slot] = make_float4(d0, d1, d2, d3);
    __syncthreads();

    // redundant sensory reduce into registers (all q identical)
    float4 sn = make_float4(0.f, 0.f, 0.f, 0.f);
    float4 sd = make_float4(0.f, 0.f, 0.f, 0.f);
    #pragma unroll
    for (int qq = 0; qq < 4; ++qq) {
        const float4 a = pnum[qq][slot], b = pden[qq][slot];
        sn.x += a.x; sn.y += a.y; sn.z += a.z; sn.w += a.w;
        sd.x += b.x; sd.y += b.y; sd.z += b.z; sd.w += b.w;
    }
    __syncthreads();   // pnum/pden reused below

    // ---- 12 ODE unfolds: lane's k-range = [q*myq, (q+1)*myq) ----
    const float4*         __restrict__ pr = pc   + (q * myq) * N_DIM + slot;
    const unsigned short* __restrict__ po = pofs + (q * myq) * N_DIM + slot;

    #pragma unroll 1
    for (int step = 0; step < UNFOLDS; ++step) {
        float m0 = 0.f, m1 = 0.f, m2 = 0.f, m3 = 0.f;
        float h0 = 0.f, h1 = 0.f, h2 = 0.f, h3 = 0.f;

        #pragma unroll 4
        for (int t = 0; t < myq; ++t) {
            const float4 p   = pr[t * N_DIM];          // coalesced dwordx4
            const int    off = (int)po[t * N_DIM];     // coalesced u16 (real i<<4)
            const float4 vv  = *(const float4*)((const char*)v4 + off);  // b128 gather
            MQUAD(p, vv.x, vv.y, vv.z, vv.w, m0, h0, m1, h1, m2, h2, m3, h3)
        }

        const float4 vo = v4[col];   // read old v (real col) BEFORE the barrier
        pnum[q][slot] = make_float4(m0, m1, m2, m3);
        pden[q][slot] = make_float4(h0, h1, h2, h3);
        __syncthreads();

        // redundant combine in all q-groups (bitwise-identical results);
        // Montgomery for the 4 division denominators (all > cg > 0).
        float4 tn = sn, td = sd;
        #pragma unroll
        for (int qq = 0; qq < 4; ++qq) {
            const float4 a = pnum[qq][slot], b = pden[qq][slot];
            tn.x += a.x; tn.y += a.y; tn.z += a.z; tn.w += a.w;
            td.x += b.x; td.y += b.y; td.z += b.z; td.w += b.w;
        }
        const float g0 = cg + td.x, g1 = cg + td.y;
        const float g2 = cg + td.z, g3 = cg + td.w;
        const float b01 = g0 * g1, b23 = g2 * g3;
        const float ip   = FRCP(b01 * b23);
        const float ip01 = b23 * ip, ip23 = b01 * ip;
        float4 vn;
        vn.x = (fmaf(cmt, vo.x, glv) + tn.x) * (g1 * ip01);
        vn.y = (fmaf(cmt, vo.y, glv) + tn.y) * (g0 * ip01);
        vn.z = (fmaf(cmt, vo.z, glv) + tn.z) * (g3 * ip23);
        vn.w = (fmaf(cmt, vo.w, glv) + tn.w) * (g2 * ip23);
        v4[col] = vn;              // scatter by perm; 4 writers, identical bits
        __syncthreads();
    }

    // writeback: scatter to real column (once per kernel)
    out[(b0 + q) * N_DIM + col] = ((const float*)v4)[(col << 2) + q];
}

extern "C" void kernel_launch(void* const* d_in, const int* in_sizes, int n_in,
                              void* d_out, int out_size, void* d_ws, size_t ws_size,
                              hipStream_t stream)
{
    const float* inputs = (const float*)d_in[0];
    const float* state  = (const float*)d_in[1];
    const float* gleak  = (const float*)d_in[2];
    const float* vleak  = (const float*)d_in[3];
    const float* cm     = (const float*)d_in[4];
    const float* w      = (const float*)d_in[5];
    const float* sigma  = (const float*)d_in[6];
    const float* mu     = (const float*)d_in[7];
    const float* erev   = (const float*)d_in[8];
    const float* sw     = (const float*)d_in[9];
    const float* ssig   = (const float*)d_in[10];
    const float* smu    = (const float*)d_in[11];
    const float* serev  = (const float*)d_in[12];
    const float* mask   = (const float*)d_in[13];
    const float* smask  = (const float*)d_in[14];

    float4* s4 = (float4*)d_ws;                        // [S*N]    = 256 KiB
    float4* pj = s4 + S_DIM * N_DIM;                   // [N]      = 4 KiB
    float4* pc = pj + N_DIM;                           // [KMAX*N] = 1 MiB
    unsigned short* pofs = (unsigned short*)(pc + KMAX * N_DIM);  // = 128 KiB
    int* cnt    = (int*)(pofs + KMAX * N_DIM);         // [N]
    int* perm   = cnt + N_DIM;                         // [N]
    int* slotof = perm + N_DIM;                        // [N]
    int* qm     = slotof + N_DIM;                      // [N]

    ltc_count<<<N_DIM, 256, 0, stream>>>(mask, cnt);
    ltc_sort<<<1, N_DIM, 0, stream>>>(cnt, perm, slotof, qm);

    ltc_precompute_s<<<(S_DIM * N_DIM + 255) / 256, 256, 0, stream>>>(
        gleak, vleak, cm, sw, ssig, smu, serev, smask, slotof, s4, pj);

    ltc_compact<<<N_DIM, 256, 0, stream>>>(w, sigma, mu, erev, mask, slotof, pc, pofs);

    ltc_main<<<B_TOT / 4, 1024, 0, stream>>>(inputs, state, pc, pofs, perm, qm,
                                             s4, pj, (float*)d_out);
}

// Round 15
// 167.805 us; speedup vs baseline: 1.0043x; 1.0027x over previous
//
#include <hip/hip_runtime.h>
#include <math.h>

#define B_TOT   1024
#define S_DIM   64
#define N_DIM   256
#define UNFOLDS 12
#define EPSF    1e-8f
#define L2E     1.4426950408889634f
#define KMAX    256
#define ECLAMP  1073741824.0f   // 2^30: clamp err <= 2^-30; quad product <= 2^121 (finite)

// Guaranteed-native transcendentals.
#if defined(__has_builtin)
#  if __has_builtin(__builtin_amdgcn_exp2f)
#    define FEXP2(x) __builtin_amdgcn_exp2f(x)
#  endif
#  if __has_builtin(__builtin_amdgcn_rcpf)
#    define FRCP(x) __builtin_amdgcn_rcpf(x)
#  endif
#endif
#ifndef FEXP2
__device__ __forceinline__ float __fexp2_asm(float x){ float r; asm("v_exp_f32 %0, %1" : "=v"(r) : "v"(x)); return r; }
#  define FEXP2(x) __fexp2_asm(x)
#endif
#ifndef FRCP
__device__ __forceinline__ float __frcp_asm(float x){ float r; asm("v_rcp_f32 %0, %1" : "=v"(r) : "v"(x)); return r; }
#  define FRCP(x) __frcp_asm(x)
#endif

__device__ __forceinline__ float softplus_f(float x) {
    return log1pf(expf(x));
}

// Montgomery batch-inversion quad: 4 sigmoids r_i = 1/(1+e_i) share ONE v_rcp.
// One param float4 p (same synapse), 4 v values (4 batches). ~1ulp exact.
// All macro locals underscore-prefixed (R9 lesson: caller-name collision).
#define MQUAD(p, v0, v1, v2, v3, m0, d0, m1, d1, m2, d2, m3, d3)            \
    {                                                                       \
        float _t0 = fmaf(p.x, v0, p.y);                                     \
        float _t1 = fmaf(p.x, v1, p.y);                                     \
        float _t2 = fmaf(p.x, v2, p.y);                                     \
        float _t3 = fmaf(p.x, v3, p.y);                                     \
        float _e0 = fminf(FEXP2(_t0), ECLAMP);                              \
        float _e1 = fminf(FEXP2(_t1), ECLAMP);                              \
        float _e2 = fminf(FEXP2(_t2), ECLAMP);                              \
        float _e3 = fminf(FEXP2(_t3), ECLAMP);                              \
        float _a0 = 1.0f + _e0, _a1 = 1.0f + _e1;                           \
        float _a2 = 1.0f + _e2, _a3 = 1.0f + _e3;                           \
        float _b01 = _a0 * _a1, _b23 = _a2 * _a3;                           \
        float _ip   = FRCP(_b01 * _b23);                                    \
        float _ip01 = _b23 * _ip, _ip23 = _b01 * _ip;                       \
        float _r0 = _a1 * _ip01, _r1 = _a0 * _ip01;                         \
        float _r2 = _a3 * _ip23, _r3 = _a2 * _ip23;                         \
        m0 = fmaf(p.w, _r0, m0); d0 = fmaf(p.z, _r0, d0);                   \
        m1 = fmaf(p.w, _r1, m1); d1 = fmaf(p.z, _r1, d1);                   \
        m2 = fmaf(p.w, _r2, m2); d2 = fmaf(p.z, _r2, d2);                   \
        m3 = fmaf(p.w, _r3, m3); d3 = fmaf(p.z, _r3, d3);                   \
    }

// ---- Stage 1: per-column live counts (static sparsity census) ----
__global__ __launch_bounds__(256)
void ltc_count(const float* __restrict__ mask, int* __restrict__ cnt)
{
    const int col = blockIdx.x, i = threadIdx.x;
    const bool live = mask[i * N_DIM + col] > 0.0f;
    const int lane = i & 63, wv = i >> 6;
    const unsigned long long ball = __ballot(live);
    __shared__ int wcnt[4];
    if (lane == 0) wcnt[wv] = __popcll(ball);
    __syncthreads();
    if (i == 0) cnt[col] = wcnt[0] + wcnt[1] + wcnt[2] + wcnt[3];
}

// ---- Stage 2: bitonic sort columns by live count (ascending) ----
// perm[slot]=col, slotof[col]=slot, qm[slot]=ceil(cnt/4). Waves of 64
// consecutive slots then have near-equal per-lane loop bounds.
__global__ __launch_bounds__(256)
void ltc_sort(const int* __restrict__ cnt, int* __restrict__ perm,
              int* __restrict__ slotof, int* __restrict__ qm)
{
    __shared__ int key[N_DIM];
    const int t = threadIdx.x;
    key[t] = (cnt[t] << 8) | t;
    __syncthreads();
    for (int k = 2; k <= N_DIM; k <<= 1) {
        for (int jj = k >> 1; jj > 0; jj >>= 1) {
            const int ixj = t ^ jj;
            if (ixj > t) {
                const int a = key[t], b = key[ixj];
                const bool asc = (t & k) == 0;
                if (asc ? (a > b) : (a < b)) { key[t] = b; key[ixj] = a; }
            }
            __syncthreads();
        }
    }
    const int kk = key[t];
    const int col = kk & 255;
    perm[t] = col;
    slotof[col] = t;
    qm[t] = ((kk >> 8) + 3) >> 2;
}

// ---- Stage 3a: sensory params {A,B,WE,WEr} written SLOT-major, and per-slot
// combine constants. sigmoid(sigma*(v-mu)) = 1/(1+exp2(A*v+B)).
__global__ void ltc_precompute_s(const float* __restrict__ gleak, const float* __restrict__ vleak,
                                 const float* __restrict__ cm,
                                 const float* __restrict__ sw,    const float* __restrict__ ssig,
                                 const float* __restrict__ smu,   const float* __restrict__ serev,
                                 const float* __restrict__ smask, const int* __restrict__ slotof,
                                 float4* __restrict__ s4, float4* __restrict__ pj)
{
    const int idx = blockIdx.x * blockDim.x + threadIdx.x;
    if (idx < S_DIM * N_DIM) {
        const int col = idx & (N_DIM - 1), s = idx >> 8;
        const int slot = slotof[col];
        float we = softplus_f(sw[idx]) * smask[idx];
        float sg = ssig[idx];
        float4 o;
        o.x = -L2E * sg;
        o.y =  L2E * sg * smu[idx];
        o.z =  we;
        o.w =  we * serev[idx];
        s4[s * N_DIM + slot] = o;
    }
    if (idx < N_DIM) {
        const int slot = slotof[idx];
        float g = softplus_f(gleak[idx]);
        float4 o;
        o.x = softplus_f(cm[idx]) * (float)UNFOLDS;  // cm_t
        o.y = g;
        o.z = g * vleak[idx];
        o.w = 0.0f;
        pj[slot] = o;
    }
}

// ---- Stage 3b: fused precompute + compaction into SLOT-major arrays.
// One block per column; ballot prefix-scan packs live rows. pc is k-major
// [k][slot] float4 (coalesced over lanes = consecutive slots); pofs same
// shape, u16 PRE-SHIFTED byte offsets (real i<<4). Pad to multiple of 4.
__global__ __launch_bounds__(256)
void ltc_compact(const float* __restrict__ w,    const float* __restrict__ sigma,
                 const float* __restrict__ mu,   const float* __restrict__ erev,
                 const float* __restrict__ mask, const int* __restrict__ slotof,
                 float4* __restrict__ pc, unsigned short* __restrict__ pofs)
{
    const int col = blockIdx.x;
    const int i   = threadIdx.x;
    const int idx = i * N_DIM + col;
    const int slot = slotof[col];

    const float mk = mask[idx];
    const bool live = mk > 0.0f;
    float we = softplus_f(w[idx]) * mk;
    float sg = sigma[idx];
    float4 o;
    o.x = -L2E * sg;
    o.y =  L2E * sg * mu[idx];
    o.z =  we;
    o.w =  we * erev[idx];

    const int lane = i & 63, wv = i >> 6;
    const unsigned long long ball = __ballot(live);
    const int lpre = __popcll(ball & ((1ull << lane) - 1ull));
    __shared__ int wcnt[4];
    if (lane == 0) wcnt[wv] = __popcll(ball);
    __syncthreads();
    int base = 0;
    #pragma unroll
    for (int ww = 0; ww < 4; ++ww) base += (ww < wv) ? wcnt[ww] : 0;
    const int total = wcnt[0] + wcnt[1] + wcnt[2] + wcnt[3];

    if (live) {
        const int pos = base + lpre;
        pc[pos * N_DIM + slot] = o;
        pofs[pos * N_DIM + slot] = (unsigned short)(i << 4);
    }
    const int K4 = (total + 3) & ~3;
    for (int k = total + i; k < K4; k += 256) {   // zero-pad (exact zeros)
        pc[k * N_DIM + slot] = make_float4(0.f, 0.f, 0.f, 0.f);
        pofs[k * N_DIM + slot] = 0;
    }
}

// ---- Stage 4: main. 1024 threads/block, 256 blocks, 4 batches each.
// slot = tid&255 (sorted column), q = tid>>8; lane loops EXACTLY qm[slot]
// quads (wave max ~ wave mean after sort). Per quad: 1 coalesced float4
// param + 1 coalesced u16 offset + 1 b128 LDS gather + Montgomery quad.
__global__ __launch_bounds__(1024, 2)
void ltc_main(const float* __restrict__ inputs, const float* __restrict__ state,
              const float4* __restrict__ pc, const unsigned short* __restrict__ pofs,
              const int* __restrict__ perm, const int* __restrict__ qm,
              const float4* __restrict__ s4, const float4* __restrict__ pj,
              float* __restrict__ out)
{
    __shared__ float4 v4[N_DIM];        // v[real i], component = batch
    __shared__ float4 pnum[4][N_DIM];   // partials [q][slot]
    __shared__ float4 pden[4][N_DIM];
    __shared__ float  in_lds[4][S_DIM];

    const int tid  = threadIdx.x;
    const int slot = tid & (N_DIM - 1);
    const int q    = tid >> 8;
    const int b0   = blockIdx.x << 2;

    // init v by REAL neuron id (coalesced)
    ((float*)v4)[(slot << 2) + q] = state[(b0 + q) * N_DIM + slot];
    if (tid < 4 * S_DIM) in_lds[tid >> 6][tid & 63] = inputs[b0 * S_DIM + tid];

    const int   col = perm[slot];       // real column this lane owns
    const int   myq = qm[slot];         // per-lane exact quad count
    const float4 c  = pj[slot];
    const float cmt = c.x, gl = c.y, glv = c.z;
    const float cg  = cmt + gl + EPSF;
    __syncthreads();

    // ---- sensory pass: q covers s in [16q, 16q+16), Montgomery quads ----
    float n0 = 0.f, n1 = 0.f, n2 = 0.f, n3 = 0.f;
    float d0 = 0.f, d1 = 0.f, d2 = 0.f, d3 = 0.f;
    {
        const float4* __restrict__ sr = s4 + (q << 4) * N_DIM + slot;
        const int sb = q << 4;
        #pragma unroll 4
        for (int s = 0; s < 16; ++s) {
            const float4 p = sr[s * N_DIM];
            const float i0 = in_lds[0][sb + s];
            const float i1 = in_lds[1][sb + s];
            const float i2 = in_lds[2][sb + s];
            const float i3 = in_lds[3][sb + s];
            MQUAD(p, i0, i1, i2, i3, n0, d0, n1, d1, n2, d2, n3, d3)
        }
    }
    pnum[q][slot] = make_float4(n0, n1, n2, n3);
    pden[q][slot] = make_float4(d0, d1, d2, d3);
    __syncthreads();

    // redundant sensory reduce into registers (all q identical)
    float4 sn = make_float4(0.f, 0.f, 0.f, 0.f);
    float4 sd = make_float4(0.f, 0.f, 0.f, 0.f);
    #pragma unroll
    for (int qq = 0; qq < 4; ++qq) {
        const float4 a = pnum[qq][slot], b = pden[qq][slot];
        sn.x += a.x; sn.y += a.y; sn.z += a.z; sn.w += a.w;
        sd.x += b.x; sd.y += b.y; sd.z += b.z; sd.w += b.w;
    }
    __syncthreads();   // pnum/pden reused below

    // ---- 12 ODE unfolds: lane's k-range = [q*myq, (q+1)*myq) ----
    const float4*         __restrict__ pr = pc   + (q * myq) * N_DIM + slot;
    const unsigned short* __restrict__ po = pofs + (q * myq) * N_DIM + slot;

    #pragma unroll 1
    for (int step = 0; step < UNFOLDS; ++step) {
        float m0 = 0.f, m1 = 0.f, m2 = 0.f, m3 = 0.f;
        float h0 = 0.f, h1 = 0.f, h2 = 0.f, h3 = 0.f;

        #pragma unroll 4
        for (int t = 0; t < myq; ++t) {
            const float4 p   = pr[t * N_DIM];          // coalesced dwordx4
            const int    off = (int)po[t * N_DIM];     // coalesced u16 (real i<<4)
            const float4 vv  = *(const float4*)((const char*)v4 + off);  // b128 gather
            MQUAD(p, vv.x, vv.y, vv.z, vv.w, m0, h0, m1, h1, m2, h2, m3, h3)
        }

        const float4 vo = v4[col];   // read old v (real col) BEFORE the barrier
        pnum[q][slot] = make_float4(m0, m1, m2, m3);
        pden[q][slot] = make_float4(h0, h1, h2, h3);
        __syncthreads();

        // redundant combine in all q-groups (bitwise-identical results);
        // Montgomery for the 4 division denominators (all > cg > 0).
        float4 tn = sn, td = sd;
        #pragma unroll
        for (int qq = 0; qq < 4; ++qq) {
            const float4 a = pnum[qq][slot], b = pden[qq][slot];
            tn.x += a.x; tn.y += a.y; tn.z += a.z; tn.w += a.w;
            td.x += b.x; td.y += b.y; td.z += b.z; td.w += b.w;
        }
        const float g0 = cg + td.x, g1 = cg + td.y;
        const float g2 = cg + td.z, g3 = cg + td.w;
        const float b01 = g0 * g1, b23 = g2 * g3;
        const float ip   = FRCP(b01 * b23);
        const float ip01 = b23 * ip, ip23 = b01 * ip;
        float4 vn;
        vn.x = (fmaf(cmt, vo.x, glv) + tn.x) * (g1 * ip01);
        vn.y = (fmaf(cmt, vo.y, glv) + tn.y) * (g0 * ip01);
        vn.z = (fmaf(cmt, vo.z, glv) + tn.z) * (g3 * ip23);
        vn.w = (fmaf(cmt, vo.w, glv) + tn.w) * (g2 * ip23);
        v4[col] = vn;              // scatter by perm; 4 writers, identical bits
        __syncthreads();
    }

    // writeback: scatter to real column (once per kernel)
    out[(b0 + q) * N_DIM + col] = ((const float*)v4)[(col << 2) + q];
}

extern "C" void kernel_launch(void* const* d_in, const int* in_sizes, int n_in,
                              void* d_out, int out_size, void* d_ws, size_t ws_size,
                              hipStream_t stream)
{
    const float* inputs = (const float*)d_in[0];
    const float* state  = (const float*)d_in[1];
    const float* gleak  = (const float*)d_in[2];
    const float* vleak  = (const float*)d_in[3];
    const float* cm     = (const float*)d_in[4];
    const float* w      = (const float*)d_in[5];
    const float* sigma  = (const float*)d_in[6];
    const float* mu     = (const float*)d_in[7];
    const float* erev   = (const float*)d_in[8];
    const float* sw     = (const float*)d_in[9];
    const float* ssig   = (const float*)d_in[10];
    const float* smu    = (const float*)d_in[11];
    const float* serev  = (const float*)d_in[12];
    const float* mask   = (const float*)d_in[13];
    const float* smask  = (const float*)d_in[14];

    float4* s4 = (float4*)d_ws;                        // [S*N]    = 256 KiB
    float4* pj = s4 + S_DIM * N_DIM;                   // [N]      = 4 KiB
    float4* pc = pj + N_DIM;                           // [KMAX*N] = 1 MiB
    unsigned short* pofs = (unsigned short*)(pc + KMAX * N_DIM);  // = 128 KiB
    int* cnt    = (int*)(pofs + KMAX * N_DIM);         // [N]
    int* perm   = cnt + N_DIM;                         // [N]
    int* slotof = perm + N_DIM;                        // [N]
    int* qm     = slotof + N_DIM;                      // [N]

    ltc_count<<<N_DIM, 256, 0, stream>>>(mask, cnt);
    ltc_sort<<<1, N_DIM, 0, stream>>>(cnt, perm, slotof, qm);

    ltc_precompute_s<<<(S_DIM * N_DIM + 255) / 256, 256, 0, stream>>>(
        gleak, vleak, cm, sw, ssig, smu, serev, smask, slotof, s4, pj);

    ltc_compact<<<N_DIM, 256, 0, stream>>>(w, sigma, mu, erev, mask, slotof, pc, pofs);

    ltc_main<<<B_TOT / 4, 1024, 0, stream>>>(inputs, state, pc, pofs, perm, qm,
                                             s4, pj, (float*)d_out);
}